// Round 6
// baseline (213.281 us; speedup 1.0000x reference)
//
#include <hip/hip_runtime.h>
#include <hip/hip_bf16.h>

#define NEG_SLOPE 0.2f
#define ROWB 320  // node row: ft bf16[128] | y bf16[16] | el f32[4] | er f32[4]

typedef unsigned short u16;
typedef unsigned int u32;

__device__ __forceinline__ u16 f32_to_bf16(float x) {
    u32 u = __float_as_uint(x);
    u32 r = u + 0x7fffu + ((u >> 16) & 1u);  // round-to-nearest-even
    return (u16)(r >> 16);
}

// ---------------- k_proj: projection + el/er + bf16 pack + y cast (+hist) --
// proj blocks: 16 nodes/block; thread owns cols {c,c+32,c+64,c+96} for 2 nodes.
__global__ __launch_bounds__(256) void k_proj(
    const float* __restrict__ feat, const float* __restrict__ fc_w,
    const float* __restrict__ y, const float* __restrict__ attn_l,
    const float* __restrict__ attn_r, char* __restrict__ comb,
    const int* __restrict__ dst, int* __restrict__ cnt,
    int N, int E, int projB, int histThreads) {
    __shared__ float fl[16 * 128];
    int t = threadIdx.x;
    if ((int)blockIdx.x >= projB) {
        int tid = (blockIdx.x - projB) * 256 + t;
        for (int e = tid; e < E; e += histThreads) atomicAdd(&cnt[dst[e]], 1);
        return;
    }
    int n0 = blockIdx.x * 16;
#pragma unroll
    for (int j = 0; j < 8; ++j) {
        int idx = j * 256 + t;
        int r = idx >> 7, c = idx & 127;
        int n = n0 + r;
        fl[idx] = (n < N) ? feat[(size_t)n * 128 + c] : 0.f;
    }
    {
        int jj = t >> 4, col = t & 15;
        int n = n0 + jj;
        if (n < N) {
            float yv = y[(size_t)n * 16 + col];
            *(u16*)(comb + (size_t)n * ROWB + 256 + 2 * col) = f32_to_bf16(yv);
        }
    }
    __syncthreads();

    int c = t & 31;   // cols c + 32j, j=0..3
    int g = t >> 5;   // nodes n0+2g, n0+2g+1
    float al[4], ar[4];
#pragma unroll
    for (int j = 0; j < 4; ++j) {
        al[j] = attn_l[c + 32 * j];
        ar[j] = attn_r[c + 32 * j];
    }

    float acc[2][4];
#pragma unroll
    for (int j = 0; j < 4; ++j) acc[0][j] = acc[1][j] = 0.f;

    const float* fb0 = fl + (2 * g) * 128;
    const float* fb1 = fl + (2 * g + 1) * 128;
    for (int k = 0; k < 128; k += 4) {
        float wv[4][4];
#pragma unroll
        for (int kk = 0; kk < 4; ++kk)
#pragma unroll
            for (int j = 0; j < 4; ++j)
                wv[kk][j] = fc_w[(size_t)(k + kk) * 128 + c + 32 * j];
        float4 f0 = *(const float4*)(fb0 + k);
        float4 f1 = *(const float4*)(fb1 + k);
#pragma unroll
        for (int j = 0; j < 4; ++j) {
            acc[0][j] = fmaf(f0.x, wv[0][j], acc[0][j]);
            acc[0][j] = fmaf(f0.y, wv[1][j], acc[0][j]);
            acc[0][j] = fmaf(f0.z, wv[2][j], acc[0][j]);
            acc[0][j] = fmaf(f0.w, wv[3][j], acc[0][j]);
            acc[1][j] = fmaf(f1.x, wv[0][j], acc[1][j]);
            acc[1][j] = fmaf(f1.y, wv[1][j], acc[1][j]);
            acc[1][j] = fmaf(f1.z, wv[2][j], acc[1][j]);
            acc[1][j] = fmaf(f1.w, wv[3][j], acc[1][j]);
        }
    }

#pragma unroll
    for (int nn = 0; nn < 2; ++nn) {
        int n = n0 + 2 * g + nn;
        if (n >= N) break;
        char* row = comb + (size_t)n * ROWB;
        float p[4], q[4];
#pragma unroll
        for (int j = 0; j < 4; ++j) {
            *(u16*)(row + 2 * (c + 32 * j)) = f32_to_bf16(acc[nn][j]);
            p[j] = acc[nn][j] * al[j];
            q[j] = acc[nn][j] * ar[j];
        }
#pragma unroll
        for (int off = 1; off < 32; off <<= 1) {
#pragma unroll
            for (int j = 0; j < 4; ++j) {
                p[j] += __shfl_xor(p[j], off);
                q[j] += __shfl_xor(q[j], off);
            }
        }
        if (c == 0) {
            float* ep = (float*)(row + 288);
#pragma unroll
            for (int j = 0; j < 4; ++j) { ep[j] = p[j]; ep[4 + j] = q[j]; }
        }
    }
}

// ---------------- scan1: sentinel fill + padded block sums ----------------
__global__ __launch_bounds__(256) void k_scan1(const int* __restrict__ cnt,
                                               int* __restrict__ bsum,
                                               u16* __restrict__ ss,
                                               int N, int ssLen4, int nb) {
    int t = threadIdx.x;
    u32 pat = ((u32)N << 16) | (u32)N;
    uint2* f2 = (uint2*)ss;
    for (int i = blockIdx.x * 256 + t; i < ssLen4; i += nb * 256)
        f2[i] = make_uint2(pat, pat);

    int i = blockIdx.x * 1024 + t * 4;
    int s = 0;
    if (i + 4 <= N) {
        int4 v = *(const int4*)(cnt + i);
        s = ((v.x + 7) & ~7) + ((v.y + 7) & ~7) + ((v.z + 7) & ~7) + ((v.w + 7) & ~7);
    } else {
        for (int k = 0; k < 4; ++k)
            if (i + k < N) s += (cnt[i + k] + 7) & ~7;
    }
#pragma unroll
    for (int off = 1; off < 64; off <<= 1) s += __shfl_xor(s, off);
    __shared__ int ws[4];
    int lane = t & 63, wv = t >> 6;
    if (lane == 0) ws[wv] = s;
    __syncthreads();
    if (t == 0) bsum[blockIdx.x] = ws[0] + ws[1] + ws[2] + ws[3];
}

// ---------------- scan2: scan of block sums + sentinel comb row -----------
__global__ void k_scan2(const int* __restrict__ bsum, int* __restrict__ boff,
                        int* __restrict__ row_off, char* __restrict__ comb,
                        int nb, int N) {
    int t = threadIdx.x;
    if (t >= 64) {
        int i = t - 64;
        if (i < 80) {
            float* srow = (float*)(comb + (size_t)N * ROWB);
            srow[i] = (i >= 72 && i < 76) ? -1e30f : 0.f;
        }
        return;
    }
    if (nb > 64) {
        if (t == 0) {
            int r = 0;
            for (int i = 0; i < nb; ++i) { boff[i] = r; r += bsum[i]; }
            row_off[N] = r;
        }
        return;
    }
    int v = (t < nb) ? bsum[t] : 0;
    int incl = v;
#pragma unroll
    for (int off = 1; off < 64; off <<= 1) {
        int u = __shfl_up(incl, off);
        if (t >= off) incl += u;
    }
    if (t < nb) boff[t] = incl - v;
    if (t == nb - 1) row_off[N] = incl;
}

// ---------------- scan3: padded per-element offsets -----------------------
__global__ __launch_bounds__(256) void k_scan3(const int* __restrict__ cnt,
                                               const int* __restrict__ boff,
                                               int* __restrict__ row_off,
                                               int* __restrict__ cursor, int N) {
    int t = threadIdx.x;
    int i = blockIdx.x * 1024 + t * 4;
    int4 v = make_int4(0, 0, 0, 0);
    if (i + 4 <= N) {
        v = *(const int4*)(cnt + i);
    } else {
        if (i < N) v.x = cnt[i];
        if (i + 1 < N) v.y = cnt[i + 1];
        if (i + 2 < N) v.z = cnt[i + 2];
        if (i + 3 < N) v.w = cnt[i + 3];
    }
    v.x = (v.x + 7) & ~7; v.y = (v.y + 7) & ~7;
    v.z = (v.z + 7) & ~7; v.w = (v.w + 7) & ~7;
    int s = v.x + v.y + v.z + v.w;
    int lane = t & 63, wv = t >> 6;
    int incl = s;
#pragma unroll
    for (int off = 1; off < 64; off <<= 1) {
        int u = __shfl_up(incl, off);
        if (lane >= off) incl += u;
    }
    __shared__ int wsum[4];
    if (lane == 63) wsum[wv] = incl;
    __syncthreads();
    int wo = boff[blockIdx.x];
    for (int k = 0; k < wv; ++k) wo += wsum[k];
    int4 o;
    o.x = wo + incl - s;
    o.y = o.x + v.x;
    o.z = o.y + v.y;
    o.w = o.z + v.z;
    if (i + 4 <= N) {
        *(int4*)(row_off + i) = o;
        *(int4*)(cursor + i) = o;
    } else {
        if (i < N) { row_off[i] = o.x; cursor[i] = o.x; }
        if (i + 1 < N) { row_off[i + 1] = o.y; cursor[i + 1] = o.y; }
        if (i + 2 < N) { row_off[i + 2] = o.z; cursor[i + 2] = o.z; }
        if (i + 3 < N) { row_off[i + 3] = o.w; cursor[i + 3] = o.w; }
    }
}

// ---------------- scatter edge ids (u16) into padded CSR order ------------
__global__ void k_scatter(const int* __restrict__ src, const int* __restrict__ dst,
                          int* __restrict__ cursor, u16* __restrict__ sst, int E) {
    int i = (blockIdx.x * 256 + threadIdx.x) * 4;
    if (i + 4 <= E) {
        int4 d = *(const int4*)(dst + i);
        int4 s = *(const int4*)(src + i);
        sst[atomicAdd(&cursor[d.x], 1)] = (u16)s.x;
        sst[atomicAdd(&cursor[d.y], 1)] = (u16)s.y;
        sst[atomicAdd(&cursor[d.z], 1)] = (u16)s.z;
        sst[atomicAdd(&cursor[d.w], 1)] = (u16)s.w;
    } else {
        for (int k = 0; k < 4 && i + k < E; ++k) {
            int p = atomicAdd(&cursor[dst[i + k]], 1);
            sst[p] = (u16)src[i + k];
        }
    }
}

// ---------------- gather aggregation: one wave per node, mask-free --------
__global__ __launch_bounds__(256) void k_agg(
    const char* __restrict__ comb, const float* __restrict__ bias,
    const int* __restrict__ row_off, const u16* __restrict__ ss,
    float* __restrict__ rst, float* __restrict__ yp, int N) {
    int w = (int)((blockIdx.x * (size_t)blockDim.x + threadIdx.x) >> 6);
    int lane = threadIdx.x & 63;
    if (w >= N) return;

    bool is_ft = lane < 32;
    int cg = (lane - 32) & 3;
    int head = (is_ft ? (lane >> 3) : ((lane - 32) >> 2)) & 3;
    int voff = is_ft ? 8 * lane : (256 + 8 * cg);
    int eoff = 288 + 4 * head;

    float er_l = *(const float*)(comb + (size_t)w * ROWB + 304 + 4 * head);

    int beg = row_off[w], end = row_off[w + 1];
    float4 acc = make_float4(0.f, 0.f, 0.f, 0.f);
    float ssum = 0.f;

#define LOADE(idx, V, EV)                                       \
    {                                                           \
        int s_ = __builtin_amdgcn_readlane(my_s, (idx));        \
        const char* rb_ = comb + (size_t)s_ * ROWB;             \
        V = *(const uint2*)(rb_ + voff);                        \
        EV = *(const float*)(rb_ + eoff);                       \
    }
#define COMPE(V, EV)                                            \
    {                                                           \
        float e_ = EV + er_l;                                   \
        e_ = fmaxf(e_, NEG_SLOPE * e_);                         \
        float ee_ = __expf(e_);                                 \
        ssum += ee_;                                            \
        acc.x = fmaf(ee_, __uint_as_float(V.x << 16), acc.x);   \
        acc.y = fmaf(ee_, __uint_as_float(V.x & 0xffff0000u), acc.y); \
        acc.z = fmaf(ee_, __uint_as_float(V.y << 16), acc.z);   \
        acc.w = fmaf(ee_, __uint_as_float(V.y & 0xffff0000u), acc.w); \
    }
#define LOAD8A(qq)                                              \
    {                                                           \
        int b8_ = 8 * (qq);                                     \
        LOADE(b8_ + 0, va0, ea0); LOADE(b8_ + 1, va1, ea1);     \
        LOADE(b8_ + 2, va2, ea2); LOADE(b8_ + 3, va3, ea3);     \
        LOADE(b8_ + 4, va4, ea4); LOADE(b8_ + 5, va5, ea5);     \
        LOADE(b8_ + 6, va6, ea6); LOADE(b8_ + 7, va7, ea7);     \
    }
#define LOAD8B(qq)                                              \
    {                                                           \
        int b8_ = 8 * (qq);                                     \
        LOADE(b8_ + 0, vb0, eb0); LOADE(b8_ + 1, vb1, eb1);     \
        LOADE(b8_ + 2, vb2, eb2); LOADE(b8_ + 3, vb3, eb3);     \
        LOADE(b8_ + 4, vb4, eb4); LOADE(b8_ + 5, vb5, eb5);     \
        LOADE(b8_ + 6, vb6, eb6); LOADE(b8_ + 7, vb7, eb7);     \
    }
#define COMP8A                                                  \
    {                                                           \
        COMPE(va0, ea0); COMPE(va1, ea1); COMPE(va2, ea2);      \
        COMPE(va3, ea3); COMPE(va4, ea4); COMPE(va5, ea5);      \
        COMPE(va6, ea6); COMPE(va7, ea7);                       \
    }
#define COMP8B                                                  \
    {                                                           \
        COMPE(vb0, eb0); COMPE(vb1, eb1); COMPE(vb2, eb2);      \
        COMPE(vb3, eb3); COMPE(vb4, eb4); COMPE(vb5, eb5);      \
        COMPE(vb6, eb6); COMPE(vb7, eb7);                       \
    }

    for (int base = beg; base < end; base += 64) {
        int cl = min(64, end - base);   // multiple of 8
        int my_s = (int)ss[base + lane];
        int ng = cl >> 3;

        uint2 va0, va1, va2, va3, va4, va5, va6, va7;
        uint2 vb0, vb1, vb2, vb3, vb4, vb5, vb6, vb7;
        float ea0, ea1, ea2, ea3, ea4, ea5, ea6, ea7;
        float eb0, eb1, eb2, eb3, eb4, eb5, eb6, eb7;

        LOAD8A(0);
        int q = 0;
        for (; q + 2 <= ng; q += 2) {
            LOAD8B(q + 1);
            COMP8A;
            if (q + 2 < ng) LOAD8A(q + 2);
            COMP8B;
        }
        if (q < ng) COMP8A;
    }
#undef LOADE
#undef COMPE
#undef LOAD8A
#undef LOAD8B
#undef COMP8A
#undef COMP8B

    float inv = 1.f / fmaxf(ssum, 1e-9f);
    acc.x *= inv; acc.y *= inv; acc.z *= inv; acc.w *= inv;

    if (is_ft) {
        float4 b4 = *(const float4*)(bias + 4 * lane);
        acc.x += b4.x; acc.y += b4.y; acc.z += b4.z; acc.w += b4.w;
        *(float4*)(rst + (size_t)w * 128 + 4 * lane) = acc;
    } else if (lane < 48) {
        *(float4*)(yp + (size_t)w * 64 + 16 * head + 4 * cg) = acc;
    }
}

extern "C" void kernel_launch(void* const* d_in, const int* in_sizes, int n_in,
                              void* d_out, int out_size, void* d_ws, size_t ws_size,
                              hipStream_t stream) {
    const float* feat   = (const float*)d_in[0];
    const float* y      = (const float*)d_in[1];
    const float* fc_w   = (const float*)d_in[2];
    const float* attn_l = (const float*)d_in[3];
    const float* attn_r = (const float*)d_in[4];
    const float* bias   = (const float*)d_in[5];
    const int*   src    = (const int*)d_in[6];
    const int*   dst    = (const int*)d_in[7];

    const int N = in_sizes[0] / 128;  // FIN = 128
    const int E = in_sizes[6];

    char* comb = (char*)d_ws;                        // (N+1) * 320 B
    int* cnt = (int*)(comb + (size_t)(N + 1) * ROWB);// N
    int* cursor = cnt + N;                           // N
    int* row_off = cursor + N;                       // N+1 (+1 pad)
    int* bsum = row_off + N + 2;                     // 256
    int* boff = bsum + 256;                          // 256
    u16* ss = (u16*)(boff + 256);                    // E + 7N + 64 (8B-aligned)

    int ssLen = (E + 7 * N + 64 + 3) & ~3;
    int ssLen4 = ssLen >> 2;

    float* rst = (float*)d_out;                      // N*128
    float* yp = rst + (size_t)N * 128;               // N*64

    (void)hipMemsetAsync(cnt, 0, (size_t)N * sizeof(int), stream);

    const int projB = (N + 15) / 16;
    const int histB = 1024;
    const int nb = (N + 1023) / 1024;

    k_proj<<<dim3(projB + histB), dim3(256), 0, stream>>>(
        feat, fc_w, y, attn_l, attn_r, comb, dst, cnt, N, E, projB, histB * 256);
    k_scan1<<<dim3(nb), dim3(256), 0, stream>>>(cnt, bsum, ss, N, ssLen4, nb);
    k_scan2<<<dim3(1), dim3(256), 0, stream>>>(bsum, boff, row_off, comb, nb, N);
    k_scan3<<<dim3(nb), dim3(256), 0, stream>>>(cnt, boff, row_off, cursor, N);
    k_scatter<<<dim3((E + 1023) / 1024), dim3(256), 0, stream>>>(
        src, dst, cursor, ss, E);
    k_agg<<<dim3(((size_t)N * 64 + 255) / 256), dim3(256), 0, stream>>>(
        comb, bias, row_off, ss, rst, yp, N);
}